// Round 5
// baseline (396.022 us; speedup 1.0000x reference)
//
#include <hip/hip_runtime.h>
#include <float.h>

typedef __attribute__((ext_vector_type(8))) short short8;   // 8 bf16 (4 VGPRs)
typedef __attribute__((ext_vector_type(4))) float f32x4;    // MFMA C/D
typedef unsigned short u16;

// ---------------- workspace layout (float offsets), lifetime-aliased ----------------
// W      [0,131072)           : weight hi/lo planes (persistent)
// YZ     [131072,2228224)     : h1r hi/lo (p3-4)  ->  y,z fp32 (p8-9)
// FEATR  [2228224,6422528)    : xt (p2-3) -> part (p6-7) -> feat hi/lo (p9-11) -> h4 fp32 (p13-14)
// FIN    [6422528,9568256)    : h2t hi/lo (p4-8) -> fin hi/lo (p11-13)
// smalls [9568256,9652736)
static constexpr size_t OFF_W     = 0;
static constexpr size_t OFF_YZ    = 131072;
static constexpr size_t OFF_Zf    = 1179648;
static constexpr size_t OFF_FEATR = 2228224;
static constexpr size_t OFF_FIN   = 6422528;
static constexpr size_t OFF_XX    = 9568256;
static constexpr size_t OFF_G     = 9584640;
static constexpr size_t OFF_G3BS  = 9586176;
static constexpr size_t OFF_IDX   = 9587200;
static constexpr size_t WS_FLOATS = 9652736;   // ~38.6 MB (< 48.3 MB proven available)

// weight sub-offsets (u16 elements within each plane)
static constexpr size_t WO_DUP = 0;       // 256x128
static constexpr size_t WO_C1  = 32768;   // 64x128
static constexpr size_t WO_2A  = 40960;   // 64x128
static constexpr size_t WO_2B  = 49152;   // 64x64
static constexpr size_t WO_2C  = 53248;   // 64x64
static constexpr size_t WO_4A  = 57344;   // 256x192
static constexpr size_t WTOT   = 106496;

// async 16B global->LDS (wave-uniform base + lane*16)
__device__ __forceinline__ void gl_lds16(const void* g, void* l) {
    __builtin_amdgcn_global_load_lds(
        (const __attribute__((address_space(1))) void*)g,
        (__attribute__((address_space(3))) void*)l, 16, 0, 0);
}

__device__ __forceinline__ u16 f2bf(float x) {
    union { float f; unsigned int u; } v; v.f = x;
    unsigned int r = v.u + 0x7fffu + ((v.u >> 16) & 1u);
    return (u16)(r >> 16);
}
__device__ __forceinline__ float bf2f(u16 h) {
    union { unsigned int u; float f; } v; v.u = ((unsigned int)h) << 16;
    return v.f;
}
__device__ __forceinline__ void split2(float x, u16& h, u16& l) {
    h = f2bf(x);
    l = f2bf(x - bf2f(h));
}

// top-4 insertion, (value desc, index asc)
static __device__ __forceinline__ void ins4(float v, int m, float bv[4], int bi[4])
{
#pragma unroll
    for (int s = 0; s < 4; ++s) {
        bool better = (v > bv[s]) || (v == bv[s] && m < bi[s]);
        float tv = bv[s]; int tm = bi[s];
        bv[s] = better ? v : bv[s];
        bi[s] = better ? m : bi[s];
        v = better ? tv : v;
        m = better ? tm : m;
    }
}

// =================================================================
// split all weight matrices into bf16 hi/lo planes (one launch)
// =================================================================
__global__ __launch_bounds__(256) void wsplit(
    const float* W_dup, const float* W_c1, const float* W2a,
    const float* W2b, const float* W2c, const float* W4a,
    u16* whi, u16* wlo)
{
    int t = blockIdx.x * 256 + threadIdx.x;   // 106,496 = 416 blocks
    float v;
    if      (t < 40960) v = (t < 32768) ? W_dup[t] : W_c1[t - 32768];
    else if (t < 53248) v = (t < 49152) ? W2a[t - 40960] : W2b[t - 49152];
    else                v = (t < 57344) ? W2c[t - 53248] : W4a[t - 57344];
    u16 h, l; split2(v, h, l);
    whi[t] = h; wlo[t] = l;
}

// =================================================================
// transpose + split x: fp32 [b][128][1024] -> xt hi/lo [b*1024][128]
// =================================================================
__global__ __launch_bounds__(256) void tsplit_x(const float* x, u16* xthi, u16* xtlo)
{
    const int b = blockIdx.z, c0 = blockIdx.y * 64, n0 = blockIdx.x * 64;
    const int t = threadIdx.x;
    __shared__ float tile[64][65];
    const float* xb = x + ((size_t)b * 128 + c0) * 1024;
#pragma unroll
    for (int i = 0; i < 16; ++i) {
        int c = i * 4 + (t >> 6), n = t & 63;
        tile[c][n] = xb[(size_t)c * 1024 + n0 + n];
    }
    __syncthreads();
#pragma unroll
    for (int i = 0; i < 16; ++i) {
        int n = i * 4 + (t >> 6), c = t & 63;
        u16 h, l; split2(tile[c][n], h, l);
        const size_t o = ((size_t)b * 1024 + n0 + n) * 128 + c0 + c;
        xthi[o] = h; xtlo[o] = l;
    }
}

// =================================================================
// Generic split-bf16 MFMA conv. Activations [row][K] hi/lo planes.
// Block 256 = 4 waves; wave owns 16 rows; ct loop covers NT col-tiles of 16.
// A-frags: direct 16B global loads (held across cts). B-frags: weight rows
// (L1-hot). acc = Ah*Bh + Ah*Bl + Al*Bh (ll dropped, ~2^-18 rel).
// OMODE 0: split-bf16 out [row][Ns] (+cofs col offset)
// OMODE 1: fp32 out [row][Ns]
// OMODE 2: max over lane's 4 rows (=4 k of one n), split out [row/4][Ns]
// OMODE 3: conv1 reshape: row' = b*2048 + (n&1023) + (o&1)*1024, col = o>>1
// NOTE: no __restrict__ on A/out — conv2b runs in-place.
// =================================================================
template<int K, int NT, int OMODE, bool RELU>
__global__ __launch_bounds__(256) void conv_mf(
    const u16* __restrict__ Whi, const u16* __restrict__ Wlo, int wstride,
    const float* __restrict__ scale, const float* __restrict__ bias,
    const u16* Ahi, const u16* Alo,
    u16* ohi, u16* olo, float* of, int Ns)
{
    constexpr int KS = K / 32;
    const int t = threadIdx.x;
    const int wu = t >> 6;
    const int lane = t & 63;
    const int j = lane & 15, q = lane >> 4;
    const int n0g = blockIdx.x * 64 + wu * 16;

    short8 a_hi[KS], a_lo[KS];
    const u16* arow_h = Ahi + (size_t)(n0g + j) * K + q * 8;
    const u16* arow_l = Alo + (size_t)(n0g + j) * K + q * 8;
#pragma unroll
    for (int ks = 0; ks < KS; ++ks) {
        a_hi[ks] = *(const short8*)(arow_h + ks * 32);
        a_lo[ks] = *(const short8*)(arow_l + ks * 32);
    }

#pragma unroll
    for (int ct = 0; ct < NT; ++ct) {
        const int o = (blockIdx.y * NT + ct) * 16 + j;
        const u16* wr_h = Whi + (size_t)o * wstride + q * 8;
        const u16* wr_l = Wlo + (size_t)o * wstride + q * 8;
        f32x4 acc = (f32x4){0.f, 0.f, 0.f, 0.f};
#pragma unroll
        for (int ks = 0; ks < KS; ++ks) {
            short8 bh = *(const short8*)(wr_h + ks * 32);
            short8 bl = *(const short8*)(wr_l + ks * 32);
            acc = __builtin_amdgcn_mfma_f32_16x16x32_bf16(a_hi[ks], bh, acc, 0, 0, 0);
            acc = __builtin_amdgcn_mfma_f32_16x16x32_bf16(a_hi[ks], bl, acc, 0, 0, 0);
            acc = __builtin_amdgcn_mfma_f32_16x16x32_bf16(a_lo[ks], bh, acc, 0, 0, 0);
        }
        const float sc = scale ? scale[o] : 1.0f;
        const float bi = bias ? bias[o] : 0.0f;
        float v[4];
#pragma unroll
        for (int r = 0; r < 4; ++r) {
            v[r] = acc[r] * sc + bi;
            if (RELU) v[r] = fmaxf(v[r], 0.f);
        }
        if constexpr (OMODE == 0) {
#pragma unroll
            for (int r = 0; r < 4; ++r) {
                u16 h, l; split2(v[r], h, l);
                const size_t row = n0g + q * 4 + r;
                ohi[row * Ns + o] = h; olo[row * Ns + o] = l;
            }
        } else if constexpr (OMODE == 1) {
#pragma unroll
            for (int r = 0; r < 4; ++r)
                of[(size_t)(n0g + q * 4 + r) * Ns + o] = v[r];
        } else if constexpr (OMODE == 2) {
            float m = fmaxf(fmaxf(v[0], v[1]), fmaxf(v[2], v[3]));
            u16 h, l; split2(m, h, l);
            const size_t row = (size_t)(n0g >> 2) + q;
            ohi[row * Ns + o] = h; olo[row * Ns + o] = l;
        } else {   // OMODE 3
            const int b = n0g >> 10;
            const int nn = (n0g & 1023) + q * 4;
            const size_t rowbase = ((size_t)b << 11) + nn + ((o & 1) << 10);
            const int col = o >> 1;
#pragma unroll
            for (int r = 0; r < 4; ++r) {
                u16 h, l; split2(v[r], h, l);
                ohi[(rowbase + r) * 128 + col] = h;
                olo[(rowbase + r) * 128 + col] = l;
            }
        }
    }
}

// =================================================================
// kNN: split-bf16 MFMA, LDS-shared B, double-buffered, m-eighths.
// Score = fma(2, dot, -xx[m]) (xx[n] dropped: per-row constant).
// Grid (16 row-tiles, 8 m-eighths, 8 b) = 1024 blocks (4/CU).
// =================================================================
struct __align__(16) KBuf {
    u16 hi[4096];   // 8 chunks x 64 m x 8 bf16
    u16 lo[4096];
    float xm[64];
};

__global__ __launch_bounds__(256) void knn_mfma3(const u16* __restrict__ thi,
                                                 const u16* __restrict__ tlo,
                                                 const float* __restrict__ xx,
                                                 float* __restrict__ part)
{
    const int b    = blockIdx.z;
    const int mq   = blockIdx.y;            // m-eighth
    const int t    = threadIdx.x;
    const int wu   = __builtin_amdgcn_readfirstlane(t >> 6);
    const int lane = t & 63;
    const int j    = lane & 15;
    const int q    = lane >> 4;
    const int nrow0 = blockIdx.x * 128 + wu * 32;

    const u16* th = thi + (size_t)b * 2048 * 64;
    const u16* tl = tlo + (size_t)b * 2048 * 64;
    const float* xb = xx + (size_t)b * 2048;

    __shared__ KBuf sb[2];

    short8 ah[2][2], al[2][2];
#pragma unroll
    for (int rt = 0; rt < 2; ++rt) {
        const size_t row = (size_t)(nrow0 + rt * 16 + j) * 64;
        ah[rt][0] = *(const short8*)(th + row + q * 8);
        ah[rt][1] = *(const short8*)(th + row + 32 + q * 8);
        al[rt][0] = *(const short8*)(tl + row + q * 8);
        al[rt][1] = *(const short8*)(tl + row + 32 + q * 8);
    }

    float bv[8][4]; int bi[8][4];
#pragma unroll
    for (int r = 0; r < 8; ++r)
#pragma unroll
        for (int s = 0; s < 4; ++s) { bv[r][s] = -FLT_MAX; bi[r][s] = 0x7fffffff; }

    const int mbeg = mq * 256;

#define KNN_STAGE(BUF, M0)                                                        \
    {                                                                             \
        const u16* sh = th + (size_t)((M0) + lane) * 64;                          \
        const u16* sl = tl + (size_t)((M0) + lane) * 64;                          \
        gl_lds16(sh + (2 * wu) * 8,     &sb[BUF].hi[(2 * wu) * 512]);             \
        gl_lds16(sh + (2 * wu + 1) * 8, &sb[BUF].hi[(2 * wu + 1) * 512]);         \
        gl_lds16(sl + (2 * wu) * 8,     &sb[BUF].lo[(2 * wu) * 512]);             \
        gl_lds16(sl + (2 * wu + 1) * 8, &sb[BUF].lo[(2 * wu + 1) * 512]);         \
        if (wu == 0 && lane < 16) gl_lds16(xb + (M0) + lane * 4, &sb[BUF].xm[0]); \
    }

    KNN_STAGE(0, mbeg)

    for (int tt = 0; tt < 4; ++tt) {
        __syncthreads();
        if (tt < 3) KNN_STAGE((tt + 1) & 1, mbeg + (tt + 1) * 64)
        const KBuf& bf = sb[tt & 1];
        const int m0 = mbeg + tt * 64;

#pragma unroll
        for (int sub = 0; sub < 4; ++sub) {
            const int ml = sub * 16 + j;
            short8 bh0 = *(const short8*)&bf.hi[(q) * 512 + ml * 8];
            short8 bh1 = *(const short8*)&bf.hi[(4 + q) * 512 + ml * 8];
            short8 bl0 = *(const short8*)&bf.lo[(q) * 512 + ml * 8];
            short8 bl1 = *(const short8*)&bf.lo[(4 + q) * 512 + ml * 8];
            const float xmv = bf.xm[ml];
            const int mcol = m0 + ml;

#pragma unroll
            for (int rt = 0; rt < 2; ++rt) {
                f32x4 accA = (f32x4){0.f, 0.f, 0.f, 0.f};
                f32x4 accB = (f32x4){0.f, 0.f, 0.f, 0.f};
                accA = __builtin_amdgcn_mfma_f32_16x16x32_bf16(ah[rt][0], bh0, accA, 0, 0, 0);
                accB = __builtin_amdgcn_mfma_f32_16x16x32_bf16(ah[rt][1], bh1, accB, 0, 0, 0);
                accA = __builtin_amdgcn_mfma_f32_16x16x32_bf16(ah[rt][0], bl0, accA, 0, 0, 0);
                accB = __builtin_amdgcn_mfma_f32_16x16x32_bf16(ah[rt][1], bl1, accB, 0, 0, 0);
                accA = __builtin_amdgcn_mfma_f32_16x16x32_bf16(al[rt][0], bh0, accA, 0, 0, 0);
                accB = __builtin_amdgcn_mfma_f32_16x16x32_bf16(al[rt][1], bh1, accB, 0, 0, 0);
                accA = __builtin_amdgcn_mfma_f32_16x16x32_bf16(al[rt][0], bl0, accA, 0, 0, 0);
                accB = __builtin_amdgcn_mfma_f32_16x16x32_bf16(al[rt][1], bl1, accB, 0, 0, 0);

#pragma unroll
                for (int r = 0; r < 4; ++r) {
                    const float pdv = __builtin_fmaf(2.f, accA[r] + accB[r], -xmv);
                    float* lv = bv[rt * 4 + r];
                    int*   li = bi[rt * 4 + r];
                    if (pdv >= lv[3]) ins4(pdv, mcol, lv, li);
                }
            }
        }
    }
#undef KNN_STAGE

    // in-wave butterfly merge across the 16 j-lanes of each row
#pragma unroll
    for (int rr = 0; rr < 8; ++rr) {
#pragma unroll
        for (int mask = 1; mask < 16; mask <<= 1) {
            float pv[4]; int pi[4];
#pragma unroll
            for (int s = 0; s < 4; ++s) {
                pv[s] = __shfl_xor(bv[rr][s], mask, 64);
                pi[s] = __shfl_xor(bi[rr][s], mask, 64);
            }
#pragma unroll
            for (int s = 0; s < 4; ++s) ins4(pv[s], pi[s], bv[rr], bi[rr]);
        }
    }
    if (j == 0) {
#pragma unroll
        for (int rt = 0; rt < 2; ++rt)
#pragma unroll
            for (int r = 0; r < 4; ++r) {
                const int nrow = nrow0 + rt * 16 + q * 4 + r;
                const size_t off = (((size_t)b * 8 + mq) * 2048 + nrow) * 8;
                float4 vv; int4 ii;
                vv.x = bv[rt * 4 + r][0]; vv.y = bv[rt * 4 + r][1];
                vv.z = bv[rt * 4 + r][2]; vv.w = bv[rt * 4 + r][3];
                ii.x = bi[rt * 4 + r][0]; ii.y = bi[rt * 4 + r][1];
                ii.z = bi[rt * 4 + r][2]; ii.w = bi[rt * 4 + r][3];
                *(float4*)(part + off) = vv;
                *(int4*)(part + off + 4) = ii;
            }
    }
}

__global__ __launch_bounds__(256) void knn_merge(const float* __restrict__ part,
                                                 int* __restrict__ idxout)
{
    int t = blockIdx.x * 256 + threadIdx.x;   // 16384
    int b = t >> 11, n = t & 2047;
    float fv[4]; int fi[4];
#pragma unroll
    for (int s = 0; s < 4; ++s) { fv[s] = -FLT_MAX; fi[s] = 0x7fffffff; }
    for (int qt = 0; qt < 8; ++qt) {
        const float* p = part + (((size_t)b * 8 + qt) * 2048 + n) * 8;
        float4 pv = *(const float4*)p;
        int4   pi = *(const int4*)(p + 4);
        ins4(pv.x, pi.x, fv, fi);
        ins4(pv.y, pi.y, fv, fi);
        ins4(pv.z, pi.z, fv, fi);
        ins4(pv.w, pi.w, fv, fi);
    }
    int4 o4; o4.x = fi[0]; o4.y = fi[1]; o4.z = fi[2]; o4.w = fi[3];
    *(int4*)(idxout + ((size_t)b * 2048 + n) * 4) = o4;
}

// xx[b*2048+n] = sum_c (hi+lo)^2 from h2t rows
__global__ __launch_bounds__(256) void xx_t(const u16* __restrict__ h2thi,
                                            const u16* __restrict__ h2tlo,
                                            float* __restrict__ xx)
{
    int t = blockIdx.x * 256 + threadIdx.x;   // 16384
    const u16* rh = h2thi + (size_t)t * 64;
    const u16* rl = h2tlo + (size_t)t * 64;
    float a = 0.f;
#pragma unroll
    for (int i = 0; i < 8; ++i) {
        short8 hv = *(const short8*)(rh + i * 8);
        short8 lv = *(const short8*)(rl + i * 8);
#pragma unroll
        for (int k = 0; k < 8; ++k) {
            float v = bf2f((u16)hv[k]) + bf2f((u16)lv[k]);
            a += v * v;
        }
    }
    xx[t] = a;
}

// g[b][c] = max_n (hi+lo) over h2t columns; one 1024-thread block per b
__global__ __launch_bounds__(1024) void gmax_t(const u16* __restrict__ h2thi,
                                               const u16* __restrict__ h2tlo,
                                               float* __restrict__ g)
{
    const int b = blockIdx.x;
    const int c = threadIdx.x & 63, sl = threadIdx.x >> 6;   // 16 slices x 128 n
    float m = -FLT_MAX;
    const size_t base = (size_t)b * 2048;
    for (int i = 0; i < 128; ++i) {
        const size_t n = base + sl * 128 + i;
        float v = bf2f(h2thi[n * 64 + c]) + bf2f(h2tlo[n * 64 + c]);
        m = fmaxf(m, v);
    }
    __shared__ float red[16][64];
    red[sl][c] = m;
    __syncthreads();
    if (threadIdx.x < 64) {
        float mm = red[0][threadIdx.x];
#pragma unroll
        for (int s = 1; s < 16; ++s) mm = fmaxf(mm, red[s][threadIdx.x]);
        g[(size_t)b * 64 + threadIdx.x] = mm;
    }
}

// feat[nk][o] = relu((y[id][o] - y[n][o] + z[n][o])*s2a[o] + b2a[o]) -> split planes
__global__ __launch_bounds__(256) void feat2a_t(
    const float* __restrict__ y, const float* __restrict__ z, const int* __restrict__ idx,
    const float* __restrict__ s2a, const float* __restrict__ b2a,
    u16* __restrict__ feathi, u16* __restrict__ featlo)
{
    int t = blockIdx.x * 256 + threadIdx.x;   // 65536 rows
    int b = t >> 13, rem = t & 8191, n = rem >> 2, k = rem & 3;
    int id = idx[(((size_t)b * 2048) + n) * 4 + k];
    const float* yb = y + (size_t)b * 2048 * 64;
    const float* yn = yb + (size_t)n * 64;
    const float* yi = yb + (size_t)id * 64;
    const float* zn = z + ((size_t)b * 2048 + n) * 64;
    u16* oh = feathi + (size_t)t * 64;
    u16* ol = featlo + (size_t)t * 64;
#pragma unroll
    for (int c = 0; c < 64; c += 4) {
        float4 a  = *(const float4*)(yi + c);
        float4 bq = *(const float4*)(yn + c);
        float4 cq = *(const float4*)(zn + c);
        float4 sv = *(const float4*)(s2a + c);
        float4 bb = *(const float4*)(b2a + c);
        float v0 = fmaxf((a.x - bq.x + cq.x) * sv.x + bb.x, 0.f);
        float v1 = fmaxf((a.y - bq.y + cq.y) * sv.y + bb.y, 0.f);
        float v2 = fmaxf((a.z - bq.z + cq.z) * sv.z + bb.z, 0.f);
        float v3 = fmaxf((a.w - bq.w + cq.w) * sv.w + bb.w, 0.f);
        union { u16 u[4]; uint2 v; } ph, pl;
        split2(v0, ph.u[0], pl.u[0]);
        split2(v1, ph.u[1], pl.u[1]);
        split2(v2, ph.u[2], pl.u[2]);
        split2(v3, ph.u[3], pl.u[3]);
        *(uint2*)(oh + c) = ph.v;
        *(uint2*)(ol + c) = pl.v;
    }
}

// g3b = relu((W3b @ relu((W3a@g)*s3a+b3a))*s3b+b3b), written as hi/lo splits
__global__ __launch_bounds__(128) void gconv_kernel(
    const float* __restrict__ g,
    const float* __restrict__ W3a, const float* __restrict__ s3a, const float* __restrict__ b3a,
    const float* __restrict__ W3b, const float* __restrict__ s3b, const float* __restrict__ b3b,
    u16* __restrict__ g3bh, u16* __restrict__ g3bl)
{
    const int b = blockIdx.x;
    const int t = threadIdx.x;
    __shared__ float gl[64], ga[128];
    if (t < 64) gl[t] = g[(size_t)b * 64 + t];
    __syncthreads();
    float a = 0.f;
#pragma unroll
    for (int c = 0; c < 64; ++c) a += W3a[t * 64 + c] * gl[c];
    ga[t] = fmaxf(a * s3a[t] + b3a[t], 0.f);
    __syncthreads();
    float o = 0.f;
#pragma unroll
    for (int c = 0; c < 128; ++c) o += W3b[t * 128 + c] * ga[c];
    float v = fmaxf(o * s3b[t] + b3b[t], 0.f);
    u16 h, l; split2(v, h, l);
    g3bh[(size_t)b * 128 + t] = h;
    g3bl[(size_t)b * 128 + t] = l;
}

// fin[n][64..192) = g3b[b] broadcast (split planes)
__global__ __launch_bounds__(256) void bcast_t(const u16* __restrict__ g3bh,
                                               const u16* __restrict__ g3bl,
                                               u16* __restrict__ finhi, u16* __restrict__ finlo)
{
    int t = blockIdx.x * 256 + threadIdx.x;   // 16384 rows
    int b = t >> 11;
    const u16* sh = g3bh + (size_t)b * 128;
    const u16* sl = g3bl + (size_t)b * 128;
    u16* dh = finhi + (size_t)t * 192 + 64;
    u16* dl = finlo + (size_t)t * 192 + 64;
#pragma unroll
    for (int i = 0; i < 16; ++i) {
        *(short8*)(dh + i * 8) = *(const short8*)(sh + i * 8);
        *(short8*)(dl + i * 8) = *(const short8*)(sl + i * 8);
    }
}

// out[b][o][n] = dot(W4b[o], h4[n]) + b4b[o]; wave per n (lane covers 4 c)
__global__ __launch_bounds__(256) void conv4b_w(const float* __restrict__ h4,
    const float* __restrict__ W4b, const float* __restrict__ b4b, float* __restrict__ out)
{
    const int wu = threadIdx.x >> 6, lane = threadIdx.x & 63;
    float4 w0 = *(const float4*)(W4b + lane * 4);
    float4 w1 = *(const float4*)(W4b + 256 + lane * 4);
    float4 w2 = *(const float4*)(W4b + 512 + lane * 4);
    for (int i = 0; i < 4; ++i) {
        const int gn = (blockIdx.x * 4 + wu) * 4 + i;   // 0..16383
        float4 hv = *(const float4*)(h4 + (size_t)gn * 256 + lane * 4);
        float p0 = hv.x * w0.x + hv.y * w0.y + hv.z * w0.z + hv.w * w0.w;
        float p1 = hv.x * w1.x + hv.y * w1.y + hv.z * w1.z + hv.w * w1.w;
        float p2 = hv.x * w2.x + hv.y * w2.y + hv.z * w2.z + hv.w * w2.w;
#pragma unroll
        for (int off = 32; off > 0; off >>= 1) {
            p0 += __shfl_down(p0, off, 64);
            p1 += __shfl_down(p1, off, 64);
            p2 += __shfl_down(p2, off, 64);
        }
        if (lane == 0) {
            const int b = gn >> 11, n = gn & 2047;
            out[((size_t)b * 3 + 0) * 2048 + n] = p0 + b4b[0];
            out[((size_t)b * 3 + 1) * 2048 + n] = p1 + b4b[1];
            out[((size_t)b * 3 + 2) * 2048 + n] = p2 + b4b[2];
        }
    }
}

extern "C" void kernel_launch(void* const* d_in, const int* in_sizes, int n_in,
                              void* d_out, int out_size, void* d_ws, size_t ws_size,
                              hipStream_t stream)
{
    const float* x     = (const float*)d_in[0];
    const float* W_dup = (const float*)d_in[1];
    const float* s_dup = (const float*)d_in[2];
    const float* b_dup = (const float*)d_in[3];
    const float* W_c1  = (const float*)d_in[4];
    const float* s_c1  = (const float*)d_in[5];
    const float* b_c1  = (const float*)d_in[6];
    const float* W2a   = (const float*)d_in[7];
    const float* s2a   = (const float*)d_in[8];
    const float* b2a   = (const float*)d_in[9];
    const float* W2b   = (const float*)d_in[10];
    const float* s2b   = (const float*)d_in[11];
    const float* b2b   = (const float*)d_in[12];
    const float* W2c   = (const float*)d_in[13];
    const float* s2c   = (const float*)d_in[14];
    const float* b2c   = (const float*)d_in[15];
    const float* W3a   = (const float*)d_in[16];
    const float* s3a   = (const float*)d_in[17];
    const float* b3a   = (const float*)d_in[18];
    const float* W3b   = (const float*)d_in[19];
    const float* s3b   = (const float*)d_in[20];
    const float* b3b   = (const float*)d_in[21];
    const float* W4a   = (const float*)d_in[22];
    const float* b4a   = (const float*)d_in[23];
    const float* W4b   = (const float*)d_in[24];
    const float* b4b   = (const float*)d_in[25];

    if (ws_size < WS_FLOATS * sizeof(float)) return;

    float* ws = (float*)d_ws;
    u16* whi   = (u16*)(ws + OFF_W);
    u16* wlo   = whi + 131072;
    u16* xthi  = (u16*)(ws + OFF_FEATR);
    u16* xtlo  = xthi + 1048576;
    u16* h1rhi = (u16*)(ws + OFF_YZ);
    u16* h1rlo = h1rhi + 2097152;
    u16* h2thi = (u16*)(ws + OFF_FIN);
    u16* h2tlo = h2thi + 1048576;
    float* part = ws + OFF_FEATR;
    float* y    = ws + OFF_YZ;
    float* z    = ws + OFF_Zf;
    u16* feathi = (u16*)(ws + OFF_FEATR);
    u16* featlo = feathi + 4194304;
    u16* finhi  = (u16*)(ws + OFF_FIN);
    u16* finlo  = finhi + 3145728;
    float* h4   = ws + OFF_FEATR;
    float* xxb  = ws + OFF_XX;
    float* g    = ws + OFF_G;
    u16* g3bh   = (u16*)(ws + OFF_G3BS);
    u16* g3bl   = g3bh + 1024;
    int* idx    = (int*)(ws + OFF_IDX);
    float* out  = (float*)d_out;

    // 0) split weights; transpose+split x
    wsplit<<<416, 256, 0, stream>>>(W_dup, W_c1, W2a, W2b, W2c, W4a, whi, wlo);
    tsplit_x<<<dim3(16, 2, 8), 256, 0, stream>>>(x, xthi, xtlo);
    // 1) conv1 (K=128, Nout=256) with reshape epilogue -> h1r [b*2048][128]
    conv_mf<128, 4, 3, true><<<dim3(128, 4), 256, 0, stream>>>(
        whi + WO_DUP, wlo + WO_DUP, 128, s_dup, b_dup, xthi, xtlo, h1rhi, h1rlo, nullptr, 128);
    // 2) h2 (K=128, Nout=64) -> h2t [b*2048][64]
    conv_mf<128, 4, 0, true><<<dim3(256, 1), 256, 0, stream>>>(
        whi + WO_C1, wlo + WO_C1, 128, s_c1, b_c1, h1rhi, h1rlo, h2thi, h2tlo, nullptr, 64);
    // 3) xx + channel max
    xx_t<<<64, 256, 0, stream>>>(h2thi, h2tlo, xxb);
    gmax_t<<<8, 1024, 0, stream>>>(h2thi, h2tlo, g);
    // 4) kNN (m-eighths) + merge
    knn_mfma3<<<dim3(16, 8, 8), 256, 0, stream>>>(h2thi, h2tlo, xxb, part);
    knn_merge<<<64, 256, 0, stream>>>(part, idx);
    // 5) y = W2a[:,:64]@h2, z = W2a[:,64:]@h2 (fp32 outs)
    conv_mf<64, 4, 1, false><<<dim3(256, 1), 256, 0, stream>>>(
        whi + WO_2A, wlo + WO_2A, 128, nullptr, nullptr, h2thi, h2tlo, nullptr, nullptr, y, 64);
    conv_mf<64, 4, 1, false><<<dim3(256, 1), 256, 0, stream>>>(
        whi + WO_2A + 64, wlo + WO_2A + 64, 128, nullptr, nullptr, h2thi, h2tlo, nullptr, nullptr, z, 64);
    // 6) conv2a via gather -> feat split planes [b*8192][64]
    feat2a_t<<<256, 256, 0, stream>>>(y, z, idx, s2a, b2a, feathi, featlo);
    // 7) conv2b in-place on feat planes
    conv_mf<64, 4, 0, true><<<dim3(1024, 1), 256, 0, stream>>>(
        whi + WO_2B, wlo + WO_2B, 64, s2b, b2b, feathi, featlo, feathi, featlo, nullptr, 64);
    // 8) conv2c + max-over-k -> fin cols 0..63
    conv_mf<64, 4, 2, true><<<dim3(1024, 1), 256, 0, stream>>>(
        whi + WO_2C, wlo + WO_2C, 64, s2c, b2c, feathi, featlo, finhi, finlo, nullptr, 192);
    // 9) g-convs + broadcast into fin cols 64..191
    gconv_kernel<<<8, 128, 0, stream>>>(g, W3a, s3a, b3a, W3b, s3b, b3b, g3bh, g3bl);
    bcast_t<<<64, 256, 0, stream>>>(g3bh, g3bl, finhi, finlo);
    // 10) h4 = relu(W4a @ fin + b4a) (K=192, Nout=256) -> fp32 [b*2048][256]
    conv_mf<192, 4, 1, true><<<dim3(256, 4), 256, 0, stream>>>(
        whi + WO_4A, wlo + WO_4A, 192, nullptr, b4a, finhi, finlo, nullptr, nullptr, h4, 256);
    // 11) out = W4b @ h4 + b4b
    conv4b_w<<<1024, 256, 0, stream>>>(h4, W4b, b4b, out);
}

// Round 6
// 303.990 us; speedup vs baseline: 1.3027x; 1.3027x over previous
//
#include <hip/hip_runtime.h>
#include <float.h>

typedef __attribute__((ext_vector_type(8))) short short8;   // 8 bf16 (4 VGPRs)
typedef __attribute__((ext_vector_type(4))) float f32x4;    // MFMA C/D
typedef unsigned short u16;

// ---------------- workspace layout (float offsets), lifetime-aliased ----------------
static constexpr size_t OFF_W     = 0;          // weight hi/lo planes (persistent)
static constexpr size_t OFF_YZ    = 131072;     // h1r hi/lo -> y,z fp32
static constexpr size_t OFF_Zf    = 1179648;
static constexpr size_t OFF_FEATR = 2228224;    // xt -> knn part -> feat hi/lo
static constexpr size_t OFF_FIN   = 6422528;    // h2t hi/lo -> fin hi/lo
static constexpr size_t OFF_XX    = 9568256;    // 16384
static constexpr size_t OFF_G     = 9584640;    // gmax partials 8*16*64 = 8192
static constexpr size_t OFF_G3BS  = 9592832;    // g3b hi/lo u16
static constexpr size_t OFF_IDX   = 9593856;    // 65536 ints
static constexpr size_t WS_FLOATS = 9659392;    // ~38.6 MB

// weight sub-offsets (u16 elements within each plane)
static constexpr size_t WO_DUP = 0;       // 256x128
static constexpr size_t WO_C1  = 32768;   // 64x128
static constexpr size_t WO_2A  = 40960;   // 64x128
static constexpr size_t WO_2B  = 49152;   // 64x64
static constexpr size_t WO_2C  = 53248;   // 64x64
static constexpr size_t WO_4A  = 57344;   // 256x192

// async 16B global->LDS (wave-uniform base + lane*16)
__device__ __forceinline__ void gl_lds16(const void* g, void* l) {
    __builtin_amdgcn_global_load_lds(
        (const __attribute__((address_space(1))) void*)g,
        (__attribute__((address_space(3))) void*)l, 16, 0, 0);
}

__device__ __forceinline__ u16 f2bf(float x) {
    union { float f; unsigned int u; } v; v.f = x;
    unsigned int r = v.u + 0x7fffu + ((v.u >> 16) & 1u);
    return (u16)(r >> 16);
}
__device__ __forceinline__ float bf2f(u16 h) {
    union { unsigned int u; float f; } v; v.u = ((unsigned int)h) << 16;
    return v.f;
}
__device__ __forceinline__ void split2(float x, u16& h, u16& l) {
    h = f2bf(x);
    l = f2bf(x - bf2f(h));
}

// top-4 insertion, (value desc, index asc); inserting a non-qualifying value is a no-op
static __device__ __forceinline__ void ins4(float v, int m, float bv[4], int bi[4])
{
#pragma unroll
    for (int s = 0; s < 4; ++s) {
        bool better = (v > bv[s]) || (v == bv[s] && m < bi[s]);
        float tv = bv[s]; int tm = bi[s];
        bv[s] = better ? v : bv[s];
        bi[s] = better ? m : bi[s];
        v = better ? tv : v;
        m = better ? tm : m;
    }
}

// =================================================================
// split all weight matrices into bf16 hi/lo planes
// =================================================================
__global__ __launch_bounds__(256) void wsplit(
    const float* W_dup, const float* W_c1, const float* W2a,
    const float* W2b, const float* W2c, const float* W4a,
    u16* whi, u16* wlo)
{
    int t = blockIdx.x * 256 + threadIdx.x;   // 106,496 -> 416 blocks
    float v;
    if      (t < 40960) v = (t < 32768) ? W_dup[t] : W_c1[t - 32768];
    else if (t < 53248) v = (t < 49152) ? W2a[t - 40960] : W2b[t - 49152];
    else                v = (t < 57344) ? W2c[t - 53248] : W4a[t - 57344];
    u16 h, l; split2(v, h, l);
    whi[t] = h; wlo[t] = l;
}

// =================================================================
// transpose + split x: fp32 [b][128][1024] -> xt hi/lo [b*1024][128]
// =================================================================
__global__ __launch_bounds__(256) void tsplit_x(const float* x, u16* xthi, u16* xtlo)
{
    const int b = blockIdx.z, c0 = blockIdx.y * 64, n0 = blockIdx.x * 64;
    const int t = threadIdx.x;
    __shared__ float tile[64][65];
    const float* xb = x + ((size_t)b * 128 + c0) * 1024;
#pragma unroll
    for (int i = 0; i < 16; ++i) {
        int c = i * 4 + (t >> 6), n = t & 63;
        tile[c][n] = xb[(size_t)c * 1024 + n0 + n];
    }
    __syncthreads();
#pragma unroll
    for (int i = 0; i < 16; ++i) {
        int n = i * 4 + (t >> 6), c = t & 63;
        u16 h, l; split2(tile[c][n], h, l);
        const size_t o = ((size_t)b * 1024 + n0 + n) * 128 + c0 + c;
        xthi[o] = h; xtlo[o] = l;
    }
}

// =================================================================
// Generic split-bf16 MFMA conv. Activations [row][K] hi/lo planes.
// OMODE 0: split-bf16 out [row][Ns]        (XX: also emit xx[row]=sum v^2)
// OMODE 1: fp32 out [row][Ns]
// OMODE 2: max over lane's 4 rows (=4 k of one n), split out [row/4][Ns]
// OMODE 3: conv1 reshape epilogue
// OMODE 4: dual fp32 out (blockIdx.y selects weight col-offset 64 and of/of2)
// OMODE 5: fused final: v=relu(acc+bias); p[o] += W2[o*256+col]*v; butterfly
//          over j-lanes; write out[b][o][n] (+bias2[o]). No intermediate buffer.
// =================================================================
template<int K, int NT, int OMODE, bool RELU, bool XX = false>
__global__ __launch_bounds__(256) void conv_mf(
    const u16* __restrict__ Whi, const u16* __restrict__ Wlo, int wstride,
    const float* __restrict__ scale, const float* __restrict__ bias,
    const u16* Ahi, const u16* Alo,
    u16* ohi, u16* olo, float* of, float* of2, int Ns,
    const float* __restrict__ W2, const float* __restrict__ bias2, float* xxout)
{
    constexpr int KS = K / 32;
    const int t = threadIdx.x;
    const int wu = t >> 6;
    const int lane = t & 63;
    const int j = lane & 15, q = lane >> 4;
    const int n0g = blockIdx.x * 64 + wu * 16;

    short8 a_hi[KS], a_lo[KS];
    const u16* arow_h = Ahi + (size_t)(n0g + j) * K + q * 8;
    const u16* arow_l = Alo + (size_t)(n0g + j) * K + q * 8;
#pragma unroll
    for (int ks = 0; ks < KS; ++ks) {
        a_hi[ks] = *(const short8*)(arow_h + ks * 32);
        a_lo[ks] = *(const short8*)(arow_l + ks * 32);
    }

    const int wofs = (OMODE == 4) ? (int)(blockIdx.y * 64) : 0;
    const int obase = (OMODE == 4 || OMODE == 5) ? 0 : blockIdx.y * NT;
    float sq[4] = {0.f, 0.f, 0.f, 0.f};
    float p[3][4];
    if constexpr (OMODE == 5) {
#pragma unroll
        for (int oo = 0; oo < 3; ++oo)
#pragma unroll
            for (int r = 0; r < 4; ++r) p[oo][r] = 0.f;
    }

#pragma unroll
    for (int ct = 0; ct < NT; ++ct) {
        const int o = (obase + ct) * 16 + j;
        const u16* wr_h = Whi + (size_t)o * wstride + wofs + q * 8;
        const u16* wr_l = Wlo + (size_t)o * wstride + wofs + q * 8;
        f32x4 acc = (f32x4){0.f, 0.f, 0.f, 0.f};
#pragma unroll
        for (int ks = 0; ks < KS; ++ks) {
            short8 bh = *(const short8*)(wr_h + ks * 32);
            short8 bl = *(const short8*)(wr_l + ks * 32);
            acc = __builtin_amdgcn_mfma_f32_16x16x32_bf16(a_hi[ks], bh, acc, 0, 0, 0);
            acc = __builtin_amdgcn_mfma_f32_16x16x32_bf16(a_hi[ks], bl, acc, 0, 0, 0);
            acc = __builtin_amdgcn_mfma_f32_16x16x32_bf16(a_lo[ks], bh, acc, 0, 0, 0);
        }
        const float sc = scale ? scale[o] : 1.0f;
        const float bi = bias ? bias[o] : 0.0f;
        float v[4];
#pragma unroll
        for (int r = 0; r < 4; ++r) {
            v[r] = acc[r] * sc + bi;
            if (RELU) v[r] = fmaxf(v[r], 0.f);
            if (XX) sq[r] += v[r] * v[r];
        }
        if constexpr (OMODE == 0) {
#pragma unroll
            for (int r = 0; r < 4; ++r) {
                u16 h, l; split2(v[r], h, l);
                const size_t row = n0g + q * 4 + r;
                ohi[row * Ns + o] = h; olo[row * Ns + o] = l;
            }
        } else if constexpr (OMODE == 1) {
#pragma unroll
            for (int r = 0; r < 4; ++r)
                of[(size_t)(n0g + q * 4 + r) * Ns + o] = v[r];
        } else if constexpr (OMODE == 2) {
            float m = fmaxf(fmaxf(v[0], v[1]), fmaxf(v[2], v[3]));
            u16 h, l; split2(m, h, l);
            const size_t row = (size_t)(n0g >> 2) + q;
            ohi[row * Ns + o] = h; olo[row * Ns + o] = l;
        } else if constexpr (OMODE == 3) {
            const int b = n0g >> 10;
            const int nn = (n0g & 1023) + q * 4;
            const size_t rowbase = ((size_t)b << 11) + nn + ((o & 1) << 10);
            const int col = o >> 1;
#pragma unroll
            for (int r = 0; r < 4; ++r) {
                u16 h, l; split2(v[r], h, l);
                ohi[(rowbase + r) * 128 + col] = h;
                olo[(rowbase + r) * 128 + col] = l;
            }
        } else if constexpr (OMODE == 4) {
            float* dst = blockIdx.y ? of2 : of;
#pragma unroll
            for (int r = 0; r < 4; ++r)
                dst[(size_t)(n0g + q * 4 + r) * Ns + o] = v[r];
        } else {   // OMODE 5
            float w0 = W2[o], w1 = W2[256 + o], w2 = W2[512 + o];
#pragma unroll
            for (int r = 0; r < 4; ++r) {
                p[0][r] += w0 * v[r];
                p[1][r] += w1 * v[r];
                p[2][r] += w2 * v[r];
            }
        }
    }

    if constexpr (XX) {
#pragma unroll
        for (int r = 0; r < 4; ++r) {
#pragma unroll
            for (int mask = 1; mask < 16; mask <<= 1)
                sq[r] += __shfl_xor(sq[r], mask, 64);
        }
        if (j == 0) {
#pragma unroll
            for (int r = 0; r < 4; ++r)
                xxout[n0g + q * 4 + r] = sq[r];
        }
    }
    if constexpr (OMODE == 5) {
#pragma unroll
        for (int oo = 0; oo < 3; ++oo)
#pragma unroll
            for (int r = 0; r < 4; ++r) {
#pragma unroll
                for (int mask = 1; mask < 16; mask <<= 1)
                    p[oo][r] += __shfl_xor(p[oo][r], mask, 64);
            }
        if (j == 0) {
            const int row0 = n0g + q * 4;
            const int b = row0 >> 11;
#pragma unroll
            for (int r = 0; r < 4; ++r) {
                const int n = (row0 + r) & 2047;
#pragma unroll
                for (int oo = 0; oo < 3; ++oo)
                    of[((size_t)b * 3 + oo) * 2048 + n] = p[oo][r] + bias2[oo];
            }
        }
    }
}

// =================================================================
// kNN: split-bf16 MFMA, LDS-shared B, double-buffered, m-quarters.
// Block = 4 waves x 16 rows = 64 rows; grid (32 row-blocks, 4 mq, 8 b) = 1024.
// Score = fma(2, dot, -xx[m]) (xx[n] dropped: per-row constant).
// Batched prefilter (max over 4 subs vs row's 4th-best) + per-candidate guard.
// =================================================================
struct __align__(16) KBuf {
    u16 hi[4096];   // 8 chunks x 64 m x 8 bf16
    u16 lo[4096];
    float xm[64];
};

__global__ __launch_bounds__(256) void knn_topk(const u16* __restrict__ thi,
                                                const u16* __restrict__ tlo,
                                                const float* __restrict__ xx,
                                                float* __restrict__ part)
{
    const int b    = blockIdx.z;
    const int mq   = blockIdx.y;
    const int t    = threadIdx.x;
    const int wu   = __builtin_amdgcn_readfirstlane(t >> 6);
    const int lane = t & 63;
    const int j    = lane & 15;
    const int q    = lane >> 4;
    const int nrow0 = blockIdx.x * 64 + wu * 16;

    const u16* th = thi + (size_t)b * 2048 * 64;
    const u16* tl = tlo + (size_t)b * 2048 * 64;
    const float* xb = xx + (size_t)b * 2048;

    __shared__ KBuf sb[2];

    const size_t arow = (size_t)(nrow0 + j) * 64;
    short8 ah0 = *(const short8*)(th + arow + q * 8);
    short8 ah1 = *(const short8*)(th + arow + 32 + q * 8);
    short8 al0 = *(const short8*)(tl + arow + q * 8);
    short8 al1 = *(const short8*)(tl + arow + 32 + q * 8);

    float bv[4][4]; int bi[4][4];
#pragma unroll
    for (int r = 0; r < 4; ++r)
#pragma unroll
        for (int s = 0; s < 4; ++s) { bv[r][s] = -FLT_MAX; bi[r][s] = 0x7fffffff; }

    const int mbeg = mq * 512;

#define KNN_STAGE(BUF, M0)                                                        \
    {                                                                             \
        const u16* sh = th + (size_t)((M0) + lane) * 64;                          \
        const u16* sl = tl + (size_t)((M0) + lane) * 64;                          \
        gl_lds16(sh + (2 * wu) * 8,     &sb[BUF].hi[(2 * wu) * 512]);             \
        gl_lds16(sh + (2 * wu + 1) * 8, &sb[BUF].hi[(2 * wu + 1) * 512]);         \
        gl_lds16(sl + (2 * wu) * 8,     &sb[BUF].lo[(2 * wu) * 512]);             \
        gl_lds16(sl + (2 * wu + 1) * 8, &sb[BUF].lo[(2 * wu + 1) * 512]);         \
        if (wu == 0 && lane < 16) gl_lds16(xb + (M0) + lane * 4, &sb[BUF].xm[0]); \
    }

    KNN_STAGE(0, mbeg)

    for (int tt = 0; tt < 8; ++tt) {
        __syncthreads();
        if (tt < 7) KNN_STAGE((tt + 1) & 1, mbeg + (tt + 1) * 64)
        const KBuf& bf = sb[tt & 1];
        const int m0 = mbeg + tt * 64;

        float pds[4][4];   // [sub][r]
#pragma unroll
        for (int sub = 0; sub < 4; ++sub) {
            const int ml = sub * 16 + j;
            short8 bh0 = *(const short8*)&bf.hi[(q) * 512 + ml * 8];
            short8 bh1 = *(const short8*)&bf.hi[(4 + q) * 512 + ml * 8];
            short8 bl0 = *(const short8*)&bf.lo[(q) * 512 + ml * 8];
            short8 bl1 = *(const short8*)&bf.lo[(4 + q) * 512 + ml * 8];
            const float xmv = bf.xm[ml];
            f32x4 accA = (f32x4){0.f, 0.f, 0.f, 0.f};
            f32x4 accB = (f32x4){0.f, 0.f, 0.f, 0.f};
            accA = __builtin_amdgcn_mfma_f32_16x16x32_bf16(ah0, bh0, accA, 0, 0, 0);
            accB = __builtin_amdgcn_mfma_f32_16x16x32_bf16(ah1, bh1, accB, 0, 0, 0);
            accA = __builtin_amdgcn_mfma_f32_16x16x32_bf16(ah0, bl0, accA, 0, 0, 0);
            accB = __builtin_amdgcn_mfma_f32_16x16x32_bf16(ah1, bl1, accB, 0, 0, 0);
            accA = __builtin_amdgcn_mfma_f32_16x16x32_bf16(al0, bh0, accA, 0, 0, 0);
            accB = __builtin_amdgcn_mfma_f32_16x16x32_bf16(al1, bh1, accB, 0, 0, 0);
            accA = __builtin_amdgcn_mfma_f32_16x16x32_bf16(al0, bl0, accA, 0, 0, 0);
            accB = __builtin_amdgcn_mfma_f32_16x16x32_bf16(al1, bl1, accB, 0, 0, 0);
#pragma unroll
            for (int r = 0; r < 4; ++r)
                pds[sub][r] = __builtin_fmaf(2.f, accA[r] + accB[r], -xmv);
        }

#pragma unroll
        for (int r = 0; r < 4; ++r) {
            float mx = fmaxf(fmaxf(pds[0][r], pds[1][r]), fmaxf(pds[2][r], pds[3][r]));
            if (mx >= bv[r][3]) {
#pragma unroll
                for (int sub = 0; sub < 4; ++sub)
                    if (pds[sub][r] >= bv[r][3])
                        ins4(pds[sub][r], m0 + sub * 16 + j, bv[r], bi[r]);
            }
        }
    }
#undef KNN_STAGE

    // in-wave butterfly merge across the 16 j-lanes of each row
#pragma unroll
    for (int rr = 0; rr < 4; ++rr) {
#pragma unroll
        for (int mask = 1; mask < 16; mask <<= 1) {
            float pv[4]; int pi[4];
#pragma unroll
            for (int s = 0; s < 4; ++s) {
                pv[s] = __shfl_xor(bv[rr][s], mask, 64);
                pi[s] = __shfl_xor(bi[rr][s], mask, 64);
            }
#pragma unroll
            for (int s = 0; s < 4; ++s) ins4(pv[s], pi[s], bv[rr], bi[rr]);
        }
    }
    if (j == 0) {
#pragma unroll
        for (int r = 0; r < 4; ++r) {
            const int nrow = nrow0 + q * 4 + r;
            const size_t off = (((size_t)b * 4 + mq) * 2048 + nrow) * 8;
            float4 vv; int4 ii;
            vv.x = bv[r][0]; vv.y = bv[r][1]; vv.z = bv[r][2]; vv.w = bv[r][3];
            ii.x = bi[r][0]; ii.y = bi[r][1]; ii.z = bi[r][2]; ii.w = bi[r][3];
            *(float4*)(part + off) = vv;
            *(int4*)(part + off + 4) = ii;
        }
    }
}

__global__ __launch_bounds__(256) void knn_merge(const float* __restrict__ part,
                                                 int* __restrict__ idxout)
{
    int t = blockIdx.x * 256 + threadIdx.x;   // 16384
    int b = t >> 11, n = t & 2047;
    float fv[4]; int fi[4];
#pragma unroll
    for (int s = 0; s < 4; ++s) { fv[s] = -FLT_MAX; fi[s] = 0x7fffffff; }
    for (int qt = 0; qt < 4; ++qt) {
        const float* pp = part + (((size_t)b * 4 + qt) * 2048 + n) * 8;
        float4 pv = *(const float4*)pp;
        int4   pi = *(const int4*)(pp + 4);
        ins4(pv.x, pi.x, fv, fi);
        ins4(pv.y, pi.y, fv, fi);
        ins4(pv.z, pi.z, fv, fi);
        ins4(pv.w, pi.w, fv, fi);
    }
    int4 o4; o4.x = fi[0]; o4.y = fi[1]; o4.z = fi[2]; o4.w = fi[3];
    *(int4*)(idxout + ((size_t)b * 2048 + n) * 4) = o4;
}

// gmax partials: gp[b][slice][c] = max over 128 rows of (hi+lo)
__global__ __launch_bounds__(256) void gmaxp(const u16* __restrict__ h2thi,
                                             const u16* __restrict__ h2tlo,
                                             float* __restrict__ gp)
{
    const int bs = blockIdx.x;                  // 128 = 8 b x 16 slices
    const int b = bs >> 4, slice = bs & 15;
    const int c = threadIdx.x & 63, rg = threadIdx.x >> 6;
    float m = -FLT_MAX;
    const size_t base = (size_t)b * 2048 + slice * 128 + rg * 32;
    for (int i = 0; i < 32; ++i) {
        const size_t n = base + i;
        m = fmaxf(m, bf2f(h2thi[n * 64 + c]) + bf2f(h2tlo[n * 64 + c]));
    }
    __shared__ float red[4][64];
    red[rg][c] = m;
    __syncthreads();
    if (threadIdx.x < 64)
        gp[(size_t)bs * 64 + threadIdx.x] =
            fmaxf(fmaxf(red[0][threadIdx.x], red[1][threadIdx.x]),
                  fmaxf(red[2][threadIdx.x], red[3][threadIdx.x]));
}

// feat[nk][o] = relu((y[id][o] - y[n][o] + z[n][o])*s2a[o] + b2a[o]) -> split planes
__global__ __launch_bounds__(256) void feat2a_t(
    const float* __restrict__ y, const float* __restrict__ z, const int* __restrict__ idx,
    const float* __restrict__ s2a, const float* __restrict__ b2a,
    u16* __restrict__ feathi, u16* __restrict__ featlo)
{
    int t = blockIdx.x * 256 + threadIdx.x;   // 65536 rows
    int b = t >> 13, rem = t & 8191, n = rem >> 2, k = rem & 3;
    int id = idx[(((size_t)b * 2048) + n) * 4 + k];
    const float* yb = y + (size_t)b * 2048 * 64;
    const float* yn = yb + (size_t)n * 64;
    const float* yi = yb + (size_t)id * 64;
    const float* zn = z + ((size_t)b * 2048 + n) * 64;
    u16* oh = feathi + (size_t)t * 64;
    u16* ol = featlo + (size_t)t * 64;
#pragma unroll
    for (int c = 0; c < 64; c += 4) {
        float4 a  = *(const float4*)(yi + c);
        float4 bq = *(const float4*)(yn + c);
        float4 cq = *(const float4*)(zn + c);
        float4 sv = *(const float4*)(s2a + c);
        float4 bb = *(const float4*)(b2a + c);
        float v0 = fmaxf((a.x - bq.x + cq.x) * sv.x + bb.x, 0.f);
        float v1 = fmaxf((a.y - bq.y + cq.y) * sv.y + bb.y, 0.f);
        float v2 = fmaxf((a.z - bq.z + cq.z) * sv.z + bb.z, 0.f);
        float v3 = fmaxf((a.w - bq.w + cq.w) * sv.w + bb.w, 0.f);
        union { u16 u[4]; uint2 v; } ph, pl;
        split2(v0, ph.u[0], pl.u[0]);
        split2(v1, ph.u[1], pl.u[1]);
        split2(v2, ph.u[2], pl.u[2]);
        split2(v3, ph.u[3], pl.u[3]);
        *(uint2*)(oh + c) = ph.v;
        *(uint2*)(ol + c) = pl.v;
    }
}

// g-convs (reduces gmax partials inline) -> g3b split planes
__global__ __launch_bounds__(128) void gconv_kernel(
    const float* __restrict__ gp,
    const float* __restrict__ W3a, const float* __restrict__ s3a, const float* __restrict__ b3a,
    const float* __restrict__ W3b, const float* __restrict__ s3b, const float* __restrict__ b3b,
    u16* __restrict__ g3bh, u16* __restrict__ g3bl)
{
    const int b = blockIdx.x;
    const int t = threadIdx.x;
    __shared__ float gl[64], ga[128];
    if (t < 64) {
        float m = -FLT_MAX;
#pragma unroll
        for (int s = 0; s < 16; ++s)
            m = fmaxf(m, gp[((size_t)b * 16 + s) * 64 + t]);
        gl[t] = m;
    }
    __syncthreads();
    float a = 0.f;
#pragma unroll
    for (int c = 0; c < 64; ++c) a += W3a[t * 64 + c] * gl[c];
    ga[t] = fmaxf(a * s3a[t] + b3a[t], 0.f);
    __syncthreads();
    float o = 0.f;
#pragma unroll
    for (int c = 0; c < 128; ++c) o += W3b[t * 128 + c] * ga[c];
    float v = fmaxf(o * s3b[t] + b3b[t], 0.f);
    u16 h, l; split2(v, h, l);
    g3bh[(size_t)b * 128 + t] = h;
    g3bl[(size_t)b * 128 + t] = l;
}

// fin[n][64..192) = g3b[b] broadcast (split planes)
__global__ __launch_bounds__(256) void bcast_t(const u16* __restrict__ g3bh,
                                               const u16* __restrict__ g3bl,
                                               u16* __restrict__ finhi, u16* __restrict__ finlo)
{
    int t = blockIdx.x * 256 + threadIdx.x;   // 16384 rows
    int b = t >> 11;
    const u16* sh = g3bh + (size_t)b * 128;
    const u16* sl = g3bl + (size_t)b * 128;
    u16* dh = finhi + (size_t)t * 192 + 64;
    u16* dl = finlo + (size_t)t * 192 + 64;
#pragma unroll
    for (int i = 0; i < 16; ++i) {
        *(short8*)(dh + i * 8) = *(const short8*)(sh + i * 8);
        *(short8*)(dl + i * 8) = *(const short8*)(sl + i * 8);
    }
}

extern "C" void kernel_launch(void* const* d_in, const int* in_sizes, int n_in,
                              void* d_out, int out_size, void* d_ws, size_t ws_size,
                              hipStream_t stream)
{
    const float* x     = (const float*)d_in[0];
    const float* W_dup = (const float*)d_in[1];
    const float* s_dup = (const float*)d_in[2];
    const float* b_dup = (const float*)d_in[3];
    const float* W_c1  = (const float*)d_in[4];
    const float* s_c1  = (const float*)d_in[5];
    const float* b_c1  = (const float*)d_in[6];
    const float* W2a   = (const float*)d_in[7];
    const float* s2a   = (const float*)d_in[8];
    const float* b2a   = (const float*)d_in[9];
    const float* W2b   = (const float*)d_in[10];
    const float* s2b   = (const float*)d_in[11];
    const float* b2b   = (const float*)d_in[12];
    const float* W2c   = (const float*)d_in[13];
    const float* s2c   = (const float*)d_in[14];
    const float* b2c   = (const float*)d_in[15];
    const float* W3a   = (const float*)d_in[16];
    const float* s3a   = (const float*)d_in[17];
    const float* b3a   = (const float*)d_in[18];
    const float* W3b   = (const float*)d_in[19];
    const float* s3b   = (const float*)d_in[20];
    const float* b3b   = (const float*)d_in[21];
    const float* W4a   = (const float*)d_in[22];
    const float* b4a   = (const float*)d_in[23];
    const float* W4b   = (const float*)d_in[24];
    const float* b4b   = (const float*)d_in[25];

    if (ws_size < WS_FLOATS * sizeof(float)) return;

    float* ws = (float*)d_ws;
    u16* whi   = (u16*)(ws + OFF_W);
    u16* wlo   = whi + 131072;
    u16* xthi  = (u16*)(ws + OFF_FEATR);
    u16* xtlo  = xthi + 1048576;
    u16* h1rhi = (u16*)(ws + OFF_YZ);
    u16* h1rlo = h1rhi + 2097152;
    u16* h2thi = (u16*)(ws + OFF_FIN);
    u16* h2tlo = h2thi + 1048576;
    float* part = ws + OFF_FEATR;
    float* y    = ws + OFF_YZ;
    float* z    = ws + OFF_Zf;
    u16* feathi = (u16*)(ws + OFF_FEATR);
    u16* featlo = feathi + 4194304;
    u16* finhi  = (u16*)(ws + OFF_FIN);
    u16* finlo  = finhi + 3145728;
    float* xxb  = ws + OFF_XX;
    float* gp   = ws + OFF_G;
    u16* g3bh   = (u16*)(ws + OFF_G3BS);
    u16* g3bl   = g3bh + 1024;
    int* idx    = (int*)(ws + OFF_IDX);
    float* out  = (float*)d_out;

    // 0) split weights; transpose+split x
    wsplit<<<416, 256, 0, stream>>>(W_dup, W_c1, W2a, W2b, W2c, W4a, whi, wlo);
    tsplit_x<<<dim3(16, 2, 8), 256, 0, stream>>>(x, xthi, xtlo);
    // 1) conv1 with reshape epilogue -> h1r [b*2048][128]
    conv_mf<128, 4, 3, true><<<dim3(128, 4), 256, 0, stream>>>(
        whi + WO_DUP, wlo + WO_DUP, 128, s_dup, b_dup, xthi, xtlo,
        h1rhi, h1rlo, nullptr, nullptr, 128, nullptr, nullptr, nullptr);
    // 2) h2 -> h2t [b*2048][64], fused xx epilogue
    conv_mf<128, 4, 0, true, true><<<dim3(256, 1), 256, 0, stream>>>(
        whi + WO_C1, wlo + WO_C1, 128, s_c1, b_c1, h1rhi, h1rlo,
        h2thi, h2tlo, nullptr, nullptr, 64, nullptr, nullptr, xxb);
    // 3) gmax partials
    gmaxp<<<128, 256, 0, stream>>>(h2thi, h2tlo, gp);
    // 4) kNN (m-quarters, 64-row blocks) + merge
    knn_topk<<<dim3(32, 4, 8), 256, 0, stream>>>(h2thi, h2tlo, xxb, part);
    knn_merge<<<64, 256, 0, stream>>>(part, idx);
    // 5) y,z in one launch (dual-output)
    conv_mf<64, 4, 4, false><<<dim3(256, 2), 256, 0, stream>>>(
        whi + WO_2A, wlo + WO_2A, 128, nullptr, nullptr, h2thi, h2tlo,
        nullptr, nullptr, y, z, 64, nullptr, nullptr, nullptr);
    // 6) conv2a via gather -> feat split planes [b*8192][64]
    feat2a_t<<<256, 256, 0, stream>>>(y, z, idx, s2a, b2a, feathi, featlo);
    // 7) conv2b in-place (block reads its A rows before any write)
    conv_mf<64, 4, 0, true><<<dim3(1024, 1), 256, 0, stream>>>(
        whi + WO_2B, wlo + WO_2B, 64, s2b, b2b, feathi, featlo,
        feathi, featlo, nullptr, nullptr, 64, nullptr, nullptr, nullptr);
    // 8) conv2c + max-over-k -> fin cols 0..63
    conv_mf<64, 4, 2, true><<<dim3(1024, 1), 256, 0, stream>>>(
        whi + WO_2C, wlo + WO_2C, 64, s2c, b2c, feathi, featlo,
        finhi, finlo, nullptr, nullptr, 192, nullptr, nullptr, nullptr);
    // 9) g-convs (gmax reduce inline) + broadcast into fin cols 64..191
    gconv_kernel<<<8, 128, 0, stream>>>(gp, W3a, s3a, b3a, W3b, s3b, b3b, g3bh, g3bl);
    bcast_t<<<64, 256, 0, stream>>>(g3bh, g3bl, finhi, finlo);
    // 10) fused h4 + final projection -> out (no h4 buffer)
    conv_mf<192, 16, 5, true><<<dim3(256, 1), 256, 0, stream>>>(
        whi + WO_4A, wlo + WO_4A, 192, nullptr, b4a, finhi, finlo,
        nullptr, nullptr, out, nullptr, 256, W4b, b4b, nullptr);
}

// Round 7
// 263.698 us; speedup vs baseline: 1.5018x; 1.1528x over previous
//
#include <hip/hip_runtime.h>
#include <float.h>

typedef __attribute__((ext_vector_type(8))) short short8;   // 8 bf16 (4 VGPRs)
typedef __attribute__((ext_vector_type(4))) float f32x4;    // MFMA C/D
typedef unsigned short u16;
typedef unsigned long long u64;

// ---------------- workspace layout (float offsets), lifetime-aliased ----------------
static constexpr size_t OFF_W     = 0;          // weight hi/lo planes (persistent)
static constexpr size_t OFF_YZ    = 131072;     // h1r hi/lo -> y,z fp32
static constexpr size_t OFF_Zf    = 1179648;
static constexpr size_t OFF_FEATR = 2228224;    // xt -> knn part (u64 keys)
static constexpr size_t OFF_FIN   = 6422528;    // h2t hi/lo -> fin hi/lo
static constexpr size_t OFF_XX    = 9568256;    // 16384
static constexpr size_t OFF_G     = 9584640;    // gmax partials 8*16*64
static constexpr size_t OFF_G3BS  = 9592832;    // g3b hi/lo u16
static constexpr size_t WS_FLOATS = 9659392;    // ~38.6 MB

// weight sub-offsets (u16 elements within each plane)
static constexpr size_t WO_DUP = 0;       // 256x128
static constexpr size_t WO_C1  = 32768;   // 64x128
static constexpr size_t WO_2A  = 40960;   // 64x128
static constexpr size_t WO_2B  = 49152;   // 64x64
static constexpr size_t WO_2C  = 53248;   // 64x64
static constexpr size_t WO_4A  = 57344;   // 256x192

// async 16B global->LDS (wave-uniform base + lane*16)
__device__ __forceinline__ void gl_lds16(const void* g, void* l) {
    __builtin_amdgcn_global_load_lds(
        (const __attribute__((address_space(1))) void*)g,
        (__attribute__((address_space(3))) void*)l, 16, 0, 0);
}

__device__ __forceinline__ u16 f2bf(float x) {
    union { float f; unsigned int u; } v; v.f = x;
    unsigned int r = v.u + 0x7fffu + ((v.u >> 16) & 1u);
    return (u16)(r >> 16);
}
__device__ __forceinline__ float bf2f(u16 h) {
    union { unsigned int u; float f; } v; v.u = ((unsigned int)h) << 16;
    return v.f;
}
__device__ __forceinline__ void split2(float x, u16& h, u16& l) {
    h = f2bf(x);
    l = f2bf(x - bf2f(h));
}

// monotone float->uint map: f1>f2  <=>  map(f1)>map(f2)  (exact, no NaNs here)
__device__ __forceinline__ unsigned int fmap(float f) {
    unsigned int u = __float_as_uint(f);
    return u ^ ((unsigned int)((int)u >> 31) | 0x80000000u);
}
// key: high32 = mapped value, low32 = 2047-m  (desc value, asc index)
__device__ __forceinline__ u64 mkkey(float f, int m) {
    return ((u64)fmap(f) << 32) | (unsigned int)(2047 - m);
}
// sorted-desc top-4 insert on u64 keys
static __device__ __forceinline__ void ins4k(u64 k, u64 bk[4])
{
#pragma unroll
    for (int s = 0; s < 4; ++s) {
        bool better = k > bk[s];
        u64 t = bk[s];
        bk[s] = better ? k : bk[s];
        k = better ? t : k;
    }
}

// =================================================================
// split all weight matrices into bf16 hi/lo planes
// =================================================================
__global__ __launch_bounds__(256) void wsplit(
    const float* W_dup, const float* W_c1, const float* W2a,
    const float* W2b, const float* W2c, const float* W4a,
    u16* whi, u16* wlo)
{
    int t = blockIdx.x * 256 + threadIdx.x;   // 106,496 -> 416 blocks
    float v;
    if      (t < 40960) v = (t < 32768) ? W_dup[t] : W_c1[t - 32768];
    else if (t < 53248) v = (t < 49152) ? W2a[t - 40960] : W2b[t - 49152];
    else                v = (t < 57344) ? W2c[t - 53248] : W4a[t - 57344];
    u16 h, l; split2(v, h, l);
    whi[t] = h; wlo[t] = l;
}

// =================================================================
// transpose + split x: fp32 [b][128][1024] -> xt hi/lo [b*1024][128]
// =================================================================
__global__ __launch_bounds__(256) void tsplit_x(const float* x, u16* xthi, u16* xtlo)
{
    const int b = blockIdx.z, c0 = blockIdx.y * 64, n0 = blockIdx.x * 64;
    const int t = threadIdx.x;
    __shared__ float tile[64][65];
    const float* xb = x + ((size_t)b * 128 + c0) * 1024;
#pragma unroll
    for (int i = 0; i < 16; ++i) {
        int c = i * 4 + (t >> 6), n = t & 63;
        tile[c][n] = xb[(size_t)c * 1024 + n0 + n];
    }
    __syncthreads();
#pragma unroll
    for (int i = 0; i < 16; ++i) {
        int n = i * 4 + (t >> 6), c = t & 63;
        u16 h, l; split2(tile[c][n], h, l);
        const size_t o = ((size_t)b * 1024 + n0 + n) * 128 + c0 + c;
        xthi[o] = h; xtlo[o] = l;
    }
}

// =================================================================
// Generic split-bf16 MFMA conv. Activations [row][K] hi/lo planes.
// OMODE 0: split-bf16 out [row][Ns]   (XX: also emit xx[row]=sum v^2)
// OMODE 3: conv1 reshape epilogue
// OMODE 4: dual fp32 out (blockIdx.y selects weight col-offset 64, of/of2)
// OMODE 5: fused final: v=relu(acc+bias); p[o]+=W2[o*256+col]*v; butterfly; out
// =================================================================
template<int K, int NT, int OMODE, bool RELU, bool XX = false>
__global__ __launch_bounds__(256) void conv_mf(
    const u16* __restrict__ Whi, const u16* __restrict__ Wlo, int wstride,
    const float* __restrict__ scale, const float* __restrict__ bias,
    const u16* Ahi, const u16* Alo,
    u16* ohi, u16* olo, float* of, float* of2, int Ns,
    const float* __restrict__ W2, const float* __restrict__ bias2, float* xxout)
{
    constexpr int KS = K / 32;
    const int t = threadIdx.x;
    const int wu = t >> 6;
    const int lane = t & 63;
    const int j = lane & 15, q = lane >> 4;
    const int n0g = blockIdx.x * 64 + wu * 16;

    short8 a_hi[KS], a_lo[KS];
    const u16* arow_h = Ahi + (size_t)(n0g + j) * K + q * 8;
    const u16* arow_l = Alo + (size_t)(n0g + j) * K + q * 8;
#pragma unroll
    for (int ks = 0; ks < KS; ++ks) {
        a_hi[ks] = *(const short8*)(arow_h + ks * 32);
        a_lo[ks] = *(const short8*)(arow_l + ks * 32);
    }

    const int wofs = (OMODE == 4) ? (int)(blockIdx.y * 64) : 0;
    const int obase = (OMODE == 4 || OMODE == 5) ? 0 : blockIdx.y * NT;
    float sq[4] = {0.f, 0.f, 0.f, 0.f};
    float p[3][4];
    if constexpr (OMODE == 5) {
#pragma unroll
        for (int oo = 0; oo < 3; ++oo)
#pragma unroll
            for (int r = 0; r < 4; ++r) p[oo][r] = 0.f;
    }

#pragma unroll
    for (int ct = 0; ct < NT; ++ct) {
        const int o = (obase + ct) * 16 + j;
        const u16* wr_h = Whi + (size_t)o * wstride + wofs + q * 8;
        const u16* wr_l = Wlo + (size_t)o * wstride + wofs + q * 8;
        f32x4 acc = (f32x4){0.f, 0.f, 0.f, 0.f};
#pragma unroll
        for (int ks = 0; ks < KS; ++ks) {
            short8 bh = *(const short8*)(wr_h + ks * 32);
            short8 bl = *(const short8*)(wr_l + ks * 32);
            acc = __builtin_amdgcn_mfma_f32_16x16x32_bf16(a_hi[ks], bh, acc, 0, 0, 0);
            acc = __builtin_amdgcn_mfma_f32_16x16x32_bf16(a_hi[ks], bl, acc, 0, 0, 0);
            acc = __builtin_amdgcn_mfma_f32_16x16x32_bf16(a_lo[ks], bh, acc, 0, 0, 0);
        }
        const float sc = scale ? scale[o] : 1.0f;
        const float bi = bias ? bias[o] : 0.0f;
        float v[4];
#pragma unroll
        for (int r = 0; r < 4; ++r) {
            v[r] = acc[r] * sc + bi;
            if (RELU) v[r] = fmaxf(v[r], 0.f);
            if (XX) sq[r] += v[r] * v[r];
        }
        if constexpr (OMODE == 0) {
#pragma unroll
            for (int r = 0; r < 4; ++r) {
                u16 h, l; split2(v[r], h, l);
                const size_t row = n0g + q * 4 + r;
                ohi[row * Ns + o] = h; olo[row * Ns + o] = l;
            }
        } else if constexpr (OMODE == 3) {
            const int b = n0g >> 10;
            const int nn = (n0g & 1023) + q * 4;
            const size_t rowbase = ((size_t)b << 11) + nn + ((o & 1) << 10);
            const int col = o >> 1;
#pragma unroll
            for (int r = 0; r < 4; ++r) {
                u16 h, l; split2(v[r], h, l);
                ohi[(rowbase + r) * 128 + col] = h;
                olo[(rowbase + r) * 128 + col] = l;
            }
        } else if constexpr (OMODE == 4) {
            float* dst = blockIdx.y ? of2 : of;
#pragma unroll
            for (int r = 0; r < 4; ++r)
                dst[(size_t)(n0g + q * 4 + r) * Ns + o] = v[r];
        } else if constexpr (OMODE == 5) {
            float w0 = W2[o], w1 = W2[256 + o], w2 = W2[512 + o];
#pragma unroll
            for (int r = 0; r < 4; ++r) {
                p[0][r] += w0 * v[r];
                p[1][r] += w1 * v[r];
                p[2][r] += w2 * v[r];
            }
        }
    }

    if constexpr (XX) {
#pragma unroll
        for (int r = 0; r < 4; ++r) {
#pragma unroll
            for (int mask = 1; mask < 16; mask <<= 1)
                sq[r] += __shfl_xor(sq[r], mask, 64);
        }
        if (j == 0) {
#pragma unroll
            for (int r = 0; r < 4; ++r)
                xxout[n0g + q * 4 + r] = sq[r];
        }
    }
    if constexpr (OMODE == 5) {
#pragma unroll
        for (int oo = 0; oo < 3; ++oo)
#pragma unroll
            for (int r = 0; r < 4; ++r) {
#pragma unroll
                for (int mask = 1; mask < 16; mask <<= 1)
                    p[oo][r] += __shfl_xor(p[oo][r], mask, 64);
            }
        if (j == 0) {
            const int row0 = n0g + q * 4;
            const int b = row0 >> 11;
#pragma unroll
            for (int r = 0; r < 4; ++r) {
                const int n = (row0 + r) & 2047;
#pragma unroll
                for (int oo = 0; oo < 3; ++oo)
                    of[((size_t)b * 3 + oo) * 2048 + n] = p[oo][r] + bias2[oo];
            }
        }
    }
}

// =================================================================
// kNN: split-bf16 MFMA, LDS-shared B, double-buffered, m-HALVES, u64 keys.
// Block = 4 waves x 16 rows = 64 rows; grid (32 rowblocks, 2 mh, 8 b) = 512.
// Stream = 64 candidates/lane-row -> warm filters; key = map(v)<<32|(2047-m).
// =================================================================
struct __align__(16) KBuf {
    u16 hi[4096];   // 8 chunks x 64 m x 8 bf16
    u16 lo[4096];
    float xm[64];
};

__global__ __launch_bounds__(256) void knn_topk(const u16* __restrict__ thi,
                                                const u16* __restrict__ tlo,
                                                const float* __restrict__ xx,
                                                u64* __restrict__ part)
{
    const int b    = blockIdx.z;
    const int mh   = blockIdx.y;
    const int t    = threadIdx.x;
    const int wu   = __builtin_amdgcn_readfirstlane(t >> 6);
    const int lane = t & 63;
    const int j    = lane & 15;
    const int q    = lane >> 4;
    const int nrow0 = blockIdx.x * 64 + wu * 16;

    const u16* th = thi + (size_t)b * 2048 * 64;
    const u16* tl = tlo + (size_t)b * 2048 * 64;
    const float* xb = xx + (size_t)b * 2048;

    __shared__ KBuf sb[2];

    const size_t arow = (size_t)(nrow0 + j) * 64;
    short8 ah0 = *(const short8*)(th + arow + q * 8);
    short8 ah1 = *(const short8*)(th + arow + 32 + q * 8);
    short8 al0 = *(const short8*)(tl + arow + q * 8);
    short8 al1 = *(const short8*)(tl + arow + 32 + q * 8);

    u64 bk[4][4];
#pragma unroll
    for (int r = 0; r < 4; ++r)
#pragma unroll
        for (int s = 0; s < 4; ++s) bk[r][s] = 0ull;

    const int mbeg = mh * 1024;

#define KNN_STAGE(BUF, M0)                                                        \
    {                                                                             \
        const u16* sh = th + (size_t)((M0) + lane) * 64;                          \
        const u16* sl = tl + (size_t)((M0) + lane) * 64;                          \
        gl_lds16(sh + (2 * wu) * 8,     &sb[BUF].hi[(2 * wu) * 512]);             \
        gl_lds16(sh + (2 * wu + 1) * 8, &sb[BUF].hi[(2 * wu + 1) * 512]);         \
        gl_lds16(sl + (2 * wu) * 8,     &sb[BUF].lo[(2 * wu) * 512]);             \
        gl_lds16(sl + (2 * wu + 1) * 8, &sb[BUF].lo[(2 * wu + 1) * 512]);         \
        if (wu == 0 && lane < 16) gl_lds16(xb + (M0) + lane * 4, &sb[BUF].xm[0]); \
    }

    KNN_STAGE(0, mbeg)

    for (int tt = 0; tt < 16; ++tt) {
        __syncthreads();
        if (tt < 15) KNN_STAGE((tt + 1) & 1, mbeg + (tt + 1) * 64)
        const KBuf& bf = sb[tt & 1];
        const int m0 = mbeg + tt * 64;

        float pds[4][4];   // [sub][r]
#pragma unroll
        for (int sub = 0; sub < 4; ++sub) {
            const int ml = sub * 16 + j;
            short8 bh0 = *(const short8*)&bf.hi[(q) * 512 + ml * 8];
            short8 bh1 = *(const short8*)&bf.hi[(4 + q) * 512 + ml * 8];
            short8 bl0 = *(const short8*)&bf.lo[(q) * 512 + ml * 8];
            short8 bl1 = *(const short8*)&bf.lo[(4 + q) * 512 + ml * 8];
            const float xmv = bf.xm[ml];
            f32x4 accA = (f32x4){0.f, 0.f, 0.f, 0.f};
            f32x4 accB = (f32x4){0.f, 0.f, 0.f, 0.f};
            accA = __builtin_amdgcn_mfma_f32_16x16x32_bf16(ah0, bh0, accA, 0, 0, 0);
            accB = __builtin_amdgcn_mfma_f32_16x16x32_bf16(ah1, bh1, accB, 0, 0, 0);
            accA = __builtin_amdgcn_mfma_f32_16x16x32_bf16(ah0, bl0, accA, 0, 0, 0);
            accB = __builtin_amdgcn_mfma_f32_16x16x32_bf16(ah1, bl1, accB, 0, 0, 0);
            accA = __builtin_amdgcn_mfma_f32_16x16x32_bf16(al0, bh0, accA, 0, 0, 0);
            accB = __builtin_amdgcn_mfma_f32_16x16x32_bf16(al1, bh1, accB, 0, 0, 0);
            accA = __builtin_amdgcn_mfma_f32_16x16x32_bf16(al0, bl0, accA, 0, 0, 0);
            accB = __builtin_amdgcn_mfma_f32_16x16x32_bf16(al1, bl1, accB, 0, 0, 0);
#pragma unroll
            for (int r = 0; r < 4; ++r)
                pds[sub][r] = __builtin_fmaf(2.f, accA[r] + accB[r], -xmv);
        }

#pragma unroll
        for (int r = 0; r < 4; ++r) {
            float mx = fmaxf(fmaxf(pds[0][r], pds[1][r]), fmaxf(pds[2][r], pds[3][r]));
            if (fmap(mx) >= (unsigned int)(bk[r][3] >> 32)) {
#pragma unroll
                for (int sub = 0; sub < 4; ++sub) {
                    u64 key = mkkey(pds[sub][r], m0 + sub * 16 + j);
                    if (key > bk[r][3]) ins4k(key, bk[r]);
                }
            }
        }
    }
#undef KNN_STAGE

    // in-wave butterfly merge across the 16 j-lanes of each row
#pragma unroll
    for (int rr = 0; rr < 4; ++rr) {
#pragma unroll
        for (int mask = 1; mask < 16; mask <<= 1) {
            u64 pk[4];
#pragma unroll
            for (int s = 0; s < 4; ++s) pk[s] = __shfl_xor(bk[rr][s], mask, 64);
#pragma unroll
            for (int s = 0; s < 4; ++s) ins4k(pk[s], bk[rr]);
        }
    }
    if (j == 0) {
#pragma unroll
        for (int r = 0; r < 4; ++r) {
            const int nrow = nrow0 + q * 4 + r;
            u64* pp = part + (((size_t)b * 2 + mh) * 2048 + nrow) * 4;
            pp[0] = bk[r][0]; pp[1] = bk[r][1]; pp[2] = bk[r][2]; pp[3] = bk[r][3];
        }
    }
}

// gmax partials: gp[b][slice][c] = max over 128 rows of (hi+lo)
__global__ __launch_bounds__(256) void gmaxp(const u16* __restrict__ h2thi,
                                             const u16* __restrict__ h2tlo,
                                             float* __restrict__ gp)
{
    const int bs = blockIdx.x;                  // 128 = 8 b x 16 slices
    const int b = bs >> 4, slice = bs & 15;
    const int c = threadIdx.x & 63, rg = threadIdx.x >> 6;
    float m = -FLT_MAX;
    const size_t base = (size_t)b * 2048 + slice * 128 + rg * 32;
    for (int i = 0; i < 32; ++i) {
        const size_t n = base + i;
        m = fmaxf(m, bf2f(h2thi[n * 64 + c]) + bf2f(h2tlo[n * 64 + c]));
    }
    __shared__ float red[4][64];
    red[rg][c] = m;
    __syncthreads();
    if (threadIdx.x < 64)
        gp[(size_t)bs * 64 + threadIdx.x] =
            fmaxf(fmaxf(red[0][threadIdx.x], red[1][threadIdx.x]),
                  fmaxf(red[2][threadIdx.x], red[3][threadIdx.x]));
}

// g-convs (reduces gmax partials inline) -> g3b split planes
__global__ __launch_bounds__(128) void gconv_kernel(
    const float* __restrict__ gp,
    const float* __restrict__ W3a, const float* __restrict__ s3a, const float* __restrict__ b3a,
    const float* __restrict__ W3b, const float* __restrict__ s3b, const float* __restrict__ b3b,
    u16* __restrict__ g3bh, u16* __restrict__ g3bl)
{
    const int b = blockIdx.x;
    const int t = threadIdx.x;
    __shared__ float gl[64], ga[128];
    if (t < 64) {
        float m = -FLT_MAX;
#pragma unroll
        for (int s = 0; s < 16; ++s)
            m = fmaxf(m, gp[((size_t)b * 16 + s) * 64 + t]);
        gl[t] = m;
    }
    __syncthreads();
    float a = 0.f;
#pragma unroll
    for (int c = 0; c < 64; ++c) a += W3a[t * 64 + c] * gl[c];
    ga[t] = fmaxf(a * s3a[t] + b3a[t], 0.f);
    __syncthreads();
    float o = 0.f;
#pragma unroll
    for (int c = 0; c < 128; ++c) o += W3b[t * 128 + c] * ga[c];
    float v = fmaxf(o * s3b[t] + b3b[t], 0.f);
    u16 h, l; split2(v, h, l);
    g3bh[(size_t)b * 128 + t] = h;
    g3bl[(size_t)b * 128 + t] = l;
}

// =================================================================
// Fused: knn-merge -> feat2a -> conv2b -> conv2c -> max-k -> fin (+g3b bcast)
// Wave-synchronous: each wave owns 16 rows (4 n x 4 k) — NO barriers.
// LDS planes [64 rows][stride 72] u16 (2-way-free banks for b128 reads).
// =================================================================
__global__ __launch_bounds__(256) void fused_edge(
    const u64* __restrict__ part,
    const float* __restrict__ y, const float* __restrict__ z,
    const float* __restrict__ s2a, const float* __restrict__ b2a,
    const u16* __restrict__ w2bh, const u16* __restrict__ w2bl,
    const float* __restrict__ s2b, const float* __restrict__ b2b,
    const u16* __restrict__ w2ch, const u16* __restrict__ w2cl,
    const float* __restrict__ s2c, const float* __restrict__ b2c,
    const u16* __restrict__ g3bh, const u16* __restrict__ g3bl,
    u16* __restrict__ finhi, u16* __restrict__ finlo)
{
    const int t = threadIdx.x;
    const int wu = t >> 6;
    const int lane = t & 63;
    const int j = lane & 15, q = lane >> 4;
    const int gb = blockIdx.x;              // 1024
    const int b = gb >> 7;
    const int n0 = (gb & 127) * 16;

    __shared__ u16 plh[64 * 72];
    __shared__ u16 pll[64 * 72];
    __shared__ int sidx[64];

    // ---- merge u64 partials -> idx (wave-private: lanes 0..3 do 1 n each) ----
    if (lane < 4) {
        const int n = n0 + wu * 4 + lane;
        u64 fk[4] = {0ull, 0ull, 0ull, 0ull};
        const u64* p0 = part + (((size_t)b * 2 + 0) * 2048 + n) * 4;
        const u64* p1 = part + (((size_t)b * 2 + 1) * 2048 + n) * 4;
#pragma unroll
        for (int s = 0; s < 4; ++s) ins4k(p0[s], fk);
#pragma unroll
        for (int s = 0; s < 4; ++s) ins4k(p1[s], fk);
        int4 ii;
        ii.x = 2047 - (int)(fk[0] & 0x7ff);
        ii.y = 2047 - (int)(fk[1] & 0x7ff);
        ii.z = 2047 - (int)(fk[2] & 0x7ff);
        ii.w = 2047 - (int)(fk[3] & 0x7ff);
        *(int4*)&sidx[wu * 16 + lane * 4] = ii;
    }

    // ---- feat2a: lane handles 1 row x 16 cols ----
    {
        const int row = lane >> 2;            // 0..15 within wave
        const int c0 = (lane & 3) * 16;
        const int id = sidx[wu * 16 + row];   // same-wave LDS dep (in-order DS)
        const int nfull = n0 + wu * 4 + (row >> 2);
        const float* yb = y + (size_t)b * 2048 * 64;
        const float* yi = yb + (size_t)id * 64;
        const float* yn = yb + (size_t)nfull * 64;
        const float* zn = z + ((size_t)b * 2048 + nfull) * 64;
        u16* oh = &plh[(wu * 16 + row) * 72 + c0];
        u16* ol = &pll[(wu * 16 + row) * 72 + c0];
#pragma unroll
        for (int cc = 0; cc < 16; cc += 4) {
            const int c = c0 + cc;
            float4 a  = *(const float4*)(yi + c);
            float4 bq = *(const float4*)(yn + c);
            float4 cq = *(const float4*)(zn + c);
            float4 sv = *(const float4*)(s2a + c);
            float4 bb = *(const float4*)(b2a + c);
            float v0 = fmaxf((a.x - bq.x + cq.x) * sv.x + bb.x, 0.f);
            float v1 = fmaxf((a.y - bq.y + cq.y) * sv.y + bb.y, 0.f);
            float v2 = fmaxf((a.z - bq.z + cq.z) * sv.z + bb.z, 0.f);
            float v3 = fmaxf((a.w - bq.w + cq.w) * sv.w + bb.w, 0.f);
            union { u16 u[4]; uint2 v; } ph, pl;
            split2(v0, ph.u[0], pl.u[0]);
            split2(v1, ph.u[1], pl.u[1]);
            split2(v2, ph.u[2], pl.u[2]);
            split2(v3, ph.u[3], pl.u[3]);
            *(uint2*)(oh + cc) = ph.v;
            *(uint2*)(ol + cc) = pl.v;
        }
    }

    // ---- conv2b: A from LDS (own 16 rows), W2b from global; write back to LDS ----
    {
        const int abase = (wu * 16 + j) * 72 + q * 8;
        short8 ah0 = *(const short8*)&plh[abase];
        short8 ah1 = *(const short8*)&plh[abase + 32];
        short8 al0 = *(const short8*)&pll[abase];
        short8 al1 = *(const short8*)&pll[abase + 32];
#pragma unroll
        for (int ct = 0; ct < 4; ++ct) {
            const int o = ct * 16 + j;
            short8 bh0 = *(const short8*)(w2bh + (size_t)o * 64 + q * 8);
            short8 bh1 = *(const short8*)(w2bh + (size_t)o * 64 + 32 + q * 8);
            short8 bl0 = *(const short8*)(w2bl + (size_t)o * 64 + q * 8);
            short8 bl1 = *(const short8*)(w2bl + (size_t)o * 64 + 32 + q * 8);
            f32x4 acc = (f32x4){0.f, 0.f, 0.f, 0.f};
            acc = __builtin_amdgcn_mfma_f32_16x16x32_bf16(ah0, bh0, acc, 0, 0, 0);
            acc = __builtin_amdgcn_mfma_f32_16x16x32_bf16(ah0, bl0, acc, 0, 0, 0);
            acc = __builtin_amdgcn_mfma_f32_16x16x32_bf16(al0, bh0, acc, 0, 0, 0);
            acc = __builtin_amdgcn_mfma_f32_16x16x32_bf16(ah1, bh1, acc, 0, 0, 0);
            acc = __builtin_amdgcn_mfma_f32_16x16x32_bf16(ah1, bl1, acc, 0, 0, 0);
            acc = __builtin_amdgcn_mfma_f32_16x16x32_bf16(al1, bh1, acc, 0, 0, 0);
            const float sc = s2b[o], bi = b2b[o];
#pragma unroll
            for (int r = 0; r < 4; ++r) {
                float v = fmaxf(acc[r] * sc + bi, 0.f);
                u16 h, l; split2(v, h, l);
                const int row = wu * 16 + q * 4 + r;
                plh[row * 72 + o] = h;
                pll[row * 72 + o] = l;
            }
        }
    }

    // ---- conv2c + max-over-k -> fin cols 0..63 ----
    {
        const int abase = (wu * 16 + j) * 72 + q * 8;
        short8 ah0 = *(const short8*)&plh[abase];
        short8 ah1 = *(const short8*)&plh[abase + 32];
        short8 al0 = *(const short8*)&pll[abase];
        short8 al1 = *(const short8*)&pll[abase + 32];
        const size_t finrow = (size_t)b * 2048 + n0 + wu * 4 + q;
#pragma unroll
        for (int ct = 0; ct < 4; ++ct) {
            const int o = ct * 16 + j;
            short8 bh0 = *(const short8*)(w2ch + (size_t)o * 64 + q * 8);
            short8 bh1 = *(const short8*)(w2ch + (size_t)o * 64 + 32 + q * 8);
            short8 bl0 = *(const short8*)(w2cl + (size_t)o * 64 + q * 8);
            short8 bl1 = *(const short8*)(w2cl + (size_t)o * 64 + 32 + q * 8);
            f32x4 acc = (f32x4){0.f, 0.f, 0.f, 0.f};
            acc = __builtin_amdgcn_mfma_f32_16x16x32_bf16(ah0, bh0, acc, 0, 0, 0);
            acc = __builtin_amdgcn_mfma_f32_16x16x32_bf16(ah0, bl0, acc, 0, 0, 0);
            acc = __builtin_amdgcn_mfma_f32_16x16x32_bf16(al0, bh0, acc, 0, 0, 0);
            acc = __builtin_amdgcn_mfma_f32_16x16x32_bf16(ah1, bh1, acc, 0, 0, 0);
            acc = __builtin_amdgcn_mfma_f32_16x16x32_bf16(ah1, bl1, acc, 0, 0, 0);
            acc = __builtin_amdgcn_mfma_f32_16x16x32_bf16(al1, bh1, acc, 0, 0, 0);
            const float sc = s2c[o], bi = b2c[o];
            float m = -FLT_MAX;
#pragma unroll
            for (int r = 0; r < 4; ++r)
                m = fmaxf(m, fmaxf(acc[r] * sc + bi, 0.f));
            u16 h, l; split2(m, h, l);
            finhi[finrow * 192 + o] = h;
            finlo[finrow * 192 + o] = l;
        }

        // ---- g3b broadcast -> fin cols 64..191 (wave's 4 n rows) ----
        const int r = lane >> 4;              // 0..3
        const int chunk = lane & 15;          // 16 x 8 cols
        const size_t br = (size_t)b * 2048 + n0 + wu * 4 + r;
        short8 gh = *(const short8*)(g3bh + (size_t)b * 128 + chunk * 8);
        short8 gl = *(const short8*)(g3bl + (size_t)b * 128 + chunk * 8);
        *(short8*)(finhi + br * 192 + 64 + chunk * 8) = gh;
        *(short8*)(finlo + br * 192 + 64 + chunk * 8) = gl;
    }
}

extern "C" void kernel_launch(void* const* d_in, const int* in_sizes, int n_in,
                              void* d_out, int out_size, void* d_ws, size_t ws_size,
                              hipStream_t stream)
{
    const float* x     = (const float*)d_in[0];
    const float* W_dup = (const float*)d_in[1];
    const float* s_dup = (const float*)d_in[2];
    const float* b_dup = (const float*)d_in[3];
    const float* W_c1  = (const float*)d_in[4];
    const float* s_c1  = (const float*)d_in[5];
    const float* b_c1  = (const float*)d_in[6];
    const float* W2a   = (const float*)d_in[7];
    const float* s2a   = (const float*)d_in[8];
    const float* b2a   = (const float*)d_in[9];
    const float* W2b   = (const float*)d_in[10];
    const float* s2b   = (const float*)d_in[11];
    const float* b2b   = (const float*)d_in[12];
    const float* W2c   = (const float*)d_in[13];
    const float* s2c   = (const float*)d_in[14];
    const float* b2c   = (const float*)d_in[15];
    const float* W3a   = (const float*)d_in[16];
    const float* s3a   = (const float*)d_in[17];
    const float* b3a   = (const float*)d_in[18];
    const float* W3b   = (const float*)d_in[19];
    const float* s3b   = (const float*)d_in[20];
    const float* b3b   = (const float*)d_in[21];
    const float* W4a   = (const float*)d_in[22];
    const float* b4a   = (const float*)d_in[23];
    const float* W4b   = (const float*)d_in[24];
    const float* b4b   = (const float*)d_in[25];

    if (ws_size < WS_FLOATS * sizeof(float)) return;

    float* ws = (float*)d_ws;
    u16* whi   = (u16*)(ws + OFF_W);
    u16* wlo   = whi + 131072;
    u16* xthi  = (u16*)(ws + OFF_FEATR);
    u16* xtlo  = xthi + 1048576;
    u16* h1rhi = (u16*)(ws + OFF_YZ);
    u16* h1rlo = h1rhi + 2097152;
    u16* h2thi = (u16*)(ws + OFF_FIN);
    u16* h2tlo = h2thi + 1048576;
    u64* part  = (u64*)(ws + OFF_FEATR);   // xt dead by knn time
    float* y    = ws + OFF_YZ;
    float* z    = ws + OFF_Zf;
    u16* finhi  = (u16*)(ws + OFF_FIN);    // h2t dead by fused_edge time
    u16* finlo  = finhi + 3145728;
    float* xxb  = ws + OFF_XX;
    float* gp   = ws + OFF_G;
    u16* g3bh   = (u16*)(ws + OFF_G3BS);
    u16* g3bl   = g3bh + 1024;
    float* out  = (float*)d_out;

    // 0) split weights; transpose+split x
    wsplit<<<416, 256, 0, stream>>>(W_dup, W_c1, W2a, W2b, W2c, W4a, whi, wlo);
    tsplit_x<<<dim3(16, 2, 8), 256, 0, stream>>>(x, xthi, xtlo);
    // 1) conv1 with reshape epilogue -> h1r [b*2048][128]
    conv_mf<128, 4, 3, true><<<dim3(128, 4), 256, 0, stream>>>(
        whi + WO_DUP, wlo + WO_DUP, 128, s_dup, b_dup, xthi, xtlo,
        h1rhi, h1rlo, nullptr, nullptr, 128, nullptr, nullptr, nullptr);
    // 2) h2 -> h2t [b*2048][64], fused xx epilogue
    conv_mf<128, 4, 0, true, true><<<dim3(256, 1), 256, 0, stream>>>(
        whi + WO_C1, wlo + WO_C1, 128, s_c1, b_c1, h1rhi, h1rlo,
        h2thi, h2tlo, nullptr, nullptr, 64, nullptr, nullptr, xxb);
    // 3) gmax partials
    gmaxp<<<128, 256, 0, stream>>>(h2thi, h2tlo, gp);
    // 4) kNN (m-halves, u64 keys) -> part
    knn_topk<<<dim3(32, 2, 8), 256, 0, stream>>>(h2thi, h2tlo, xxb, part);
    // 5) y,z in one launch (dual-output)
    conv_mf<64, 4, 4, false><<<dim3(256, 2), 256, 0, stream>>>(
        whi + WO_2A, wlo + WO_2A, 128, nullptr, nullptr, h2thi, h2tlo,
        nullptr, nullptr, y, z, 64, nullptr, nullptr, nullptr);
    // 6) g-convs (gmax reduce inline)
    gconv_kernel<<<8, 128, 0, stream>>>(gp, W3a, s3a, b3a, W3b, s3b, b3b, g3bh, g3bl);
    // 7) fused merge+feat2a+conv2b+conv2c+maxk+bcast -> fin
    fused_edge<<<1024, 256, 0, stream>>>(
        part, y, z, s2a, b2a,
        whi + WO_2B, wlo + WO_2B, s2b, b2b,
        whi + WO_2C, wlo + WO_2C, s2c, b2c,
        g3bh, g3bl, finhi, finlo);
    // 8) fused h4 + final projection -> out
    conv_mf<192, 16, 5, true><<<dim3(256, 1), 256, 0, stream>>>(
        whi + WO_4A, wlo + WO_4A, 192, nullptr, b4a, finhi, finlo,
        nullptr, nullptr, out, nullptr, 256, W4b, b4b, nullptr);
}